// Round 2
// baseline (686.964 us; speedup 1.0000x reference)
//
#include <hip/hip_runtime.h>

// Problem constants: B=1048576, T=11, F=3, H=11, C=7
#define TT 11
#define FF 3
#define HH 11
#define CC 7
#define TF 33      // T*F
#define BLOCK 256

// ---- workspace layout (all f32) ----
// Per-j gate block, GJ dwords each:
//  [0..10]  Wz (rec_kernel col j)      [11..13] Kz (kernel col j)       [14] bz (in+rec folded)
//  [15..25] Wr                         [26..28] Kr                      [29] br (folded)
//  [30..40] Wh (recurrent, feeds rh)   [41..43] Kh (input, feeds xh)    [44] brh (rec bias, inside r*)
//  [45] bxh (input bias)               [46,47] pad
#define GJ 48
#define WS_DEN 528      // [t][c][12]: dense col c of step t, j=0..10 + pad  (11*7*12 = 924)
#define WS_DB2 1452     // [7] dense bias
// total 1459 dwords

__device__ __forceinline__ float fast_sigmoid(float a) {
    float t = __builtin_amdgcn_exp2f(-1.44269504088896340736f * a);
    return __builtin_amdgcn_rcpf(1.0f + t);
}
// tanh(a) = 2*sigmoid(2a) - 1 ; monotone-safe at +-inf, no NaN
__device__ __forceinline__ float fast_tanh(float a) {
    float t = __builtin_amdgcn_exp2f(-2.88539008177792681472f * a);
    return fmaf(2.0f, __builtin_amdgcn_rcpf(1.0f + t), -1.0f);
}

__global__ void prep_weights(const float* __restrict__ k,
                             const float* __restrict__ rk,
                             const float* __restrict__ bias,
                             const float* __restrict__ dw,
                             const float* __restrict__ db,
                             float* __restrict__ ws) {
    const int tid = threadIdx.x;
    if (tid < HH) {
        const int j = tid;
        float* g = ws + j * GJ;
        const int cz = j, cr = HH + j, ch = 2 * HH + j;
        #pragma unroll
        for (int i = 0; i < HH; ++i) {
            g[i]      = rk[i * TF + cz];
            g[15 + i] = rk[i * TF + cr];
            g[30 + i] = rk[i * TF + ch];
        }
        #pragma unroll
        for (int i = 0; i < FF; ++i) {
            g[11 + i] = k[i * TF + cz];
            g[26 + i] = k[i * TF + cr];
            g[41 + i] = k[i * TF + ch];
        }
        g[14] = bias[cz] + bias[TF + cz];
        g[29] = bias[cr] + bias[TF + cr];
        g[44] = bias[TF + ch];  // recurrent bias (multiplied by r)
        g[45] = bias[ch];       // input bias
        g[46] = 0.0f; g[47] = 0.0f;
    }
    for (int idx = tid; idx < TT * CC; idx += BLOCK) {
        const int t = idx / CC, c = idx % CC;
        float* d = ws + WS_DEN + idx * 12;   // (t*7+c)*12
        #pragma unroll
        for (int j = 0; j < HH; ++j) d[j] = dw[(t * HH + j) * CC + c];
        d[11] = 0.0f;
    }
    if (tid < CC) ws[WS_DB2 + tid] = db[tid];
}

__global__ __launch_bounds__(BLOCK, 4) void gru_main(
    const float* __restrict__ x,   // [B, T*F] f32
    const float* __restrict__ ws,  // packed f32 weights (SGPR-resident via s_load)
    float* __restrict__ out,       // [B, C]
    int Bt)
{
    __shared__ float sx[BLOCK * TF];  // 33792 B -> 4 blocks/CU by LDS
    const int tid = threadIdx.x;
    const long long base = (long long)blockIdx.x * BLOCK;

    // ---- coalesced f32 stage of x (global layout == LDS layout; no repack) ----
    {
        const long long gbase = base * TF;
        const long long gmax = (long long)Bt * TF;
        #pragma unroll
        for (int i = 0; i < TF; ++i) {
            const int e = tid + i * BLOCK;
            const long long g = gbase + e;
            sx[e] = (g < gmax) ? x[g] : 0.0f;
        }
    }
    __syncthreads();

    const float* xr = sx + tid * TF;  // stride 33 dwords: bank-conflict-free

    float ha[HH], hb[HH], lg[CC];
    #pragma unroll
    for (int c = 0; c < CC; ++c) lg[c] = ws[WS_DB2 + c];

// fused dense: logits += h_t @ dw_t, fp32 fma, SGPR weights
#define DENSE(HN, T) do { \
    const float* d_ = ws + WS_DEN + (T) * (CC * 12); \
    _Pragma("unroll") \
    for (int c = 0; c < CC; ++c) { \
        float acc = lg[c]; \
        _Pragma("unroll") \
        for (int j = 0; j < HH; ++j) acc = fmaf(HN[j], d_[c * 12 + j], acc); \
        lg[c] = acc; \
    } } while (0)

// one GRU step: reads HP (h_{t-1}), writes HN (h_t).  All weights SGPR operands.
#define STEP(HP, HN, T) do { \
    const float x0 = xr[3 * (T)], x1 = xr[3 * (T) + 1], x2 = xr[3 * (T) + 2]; \
    _Pragma("unroll") \
    for (int j = 0; j < HH; ++j) { \
        const float* g = ws + j * GJ; \
        float az = g[14], ar = g[29], arh = g[44], axh = g[45]; \
        _Pragma("unroll") \
        for (int i = 0; i < HH; ++i) { \
            az  = fmaf(HP[i], g[i],      az); \
            ar  = fmaf(HP[i], g[15 + i], ar); \
            arh = fmaf(HP[i], g[30 + i], arh); \
        } \
        az  = fmaf(x0, g[11], az);  az  = fmaf(x1, g[12], az);  az  = fmaf(x2, g[13], az); \
        ar  = fmaf(x0, g[26], ar);  ar  = fmaf(x1, g[27], ar);  ar  = fmaf(x2, g[28], ar); \
        axh = fmaf(x0, g[41], axh); axh = fmaf(x1, g[42], axh); axh = fmaf(x2, g[43], axh); \
        const float z = fast_sigmoid(az); \
        const float r = fast_sigmoid(ar); \
        const float hh = fast_tanh(fmaf(r, arh, axh)); \
        HN[j] = hh + z * (HP[j] - hh); \
    } \
    DENSE(HN, T); } while (0)

    // ---- t = 0 (h_prev = 0: recurrent terms vanish) ----
    {
        const float x0 = xr[0], x1 = xr[1], x2 = xr[2];
        #pragma unroll
        for (int j = 0; j < HH; ++j) {
            const float* g = ws + j * GJ;
            float az = g[14], ar = g[29], axh = g[45];
            const float arh = g[44];
            az  = fmaf(x0, g[11], az);  az  = fmaf(x1, g[12], az);  az  = fmaf(x2, g[13], az);
            ar  = fmaf(x0, g[26], ar);  ar  = fmaf(x1, g[27], ar);  ar  = fmaf(x2, g[28], ar);
            axh = fmaf(x0, g[41], axh); axh = fmaf(x1, g[42], axh); axh = fmaf(x2, g[43], axh);
            const float z = fast_sigmoid(az);
            const float r = fast_sigmoid(ar);
            const float hh = fast_tanh(fmaf(r, arh, axh));
            ha[j] = hh - z * hh;   // z*0 + (1-z)*hh
        }
        DENSE(ha, 0);
    }

    // ---- t = 1..10, ping-pong ha<->hb (keeps h_{t-1} intact during the j-loop) ----
    #pragma unroll 1
    for (int tt = 0; tt < 5; ++tt) {
        STEP(ha, hb, 1 + 2 * tt);
        STEP(hb, ha, 2 + 2 * tt);
    }

#undef STEP
#undef DENSE

    // ---- softmax ----
    float m = lg[0];
    #pragma unroll
    for (int c = 1; c < CC; ++c) m = fmaxf(m, lg[c]);
    float s = 0.0f;
    float e[CC];
    #pragma unroll
    for (int c = 0; c < CC; ++c) {
        e[c] = __builtin_amdgcn_exp2f((lg[c] - m) * 1.44269504088896340736f);
        s += e[c];
    }
    const float inv = __builtin_amdgcn_rcpf(s);

    // ---- staged coalesced writeback (reuse sx) ----
    __syncthreads();
    #pragma unroll
    for (int c = 0; c < CC; ++c) sx[tid * CC + c] = e[c] * inv;  // stride 7: conflict-free
    __syncthreads();
    {
        const long long obase = base * CC;
        const long long omax = (long long)Bt * CC;
        #pragma unroll
        for (int i = 0; i < CC; ++i) {
            long long g = obase + tid + i * BLOCK;
            if (g < omax) out[g] = sx[tid + i * BLOCK];
        }
    }
}

extern "C" void kernel_launch(void* const* d_in, const int* in_sizes, int n_in,
                              void* d_out, int out_size, void* d_ws, size_t ws_size,
                              hipStream_t stream) {
    const float* x  = (const float*)d_in[0];
    const float* k  = (const float*)d_in[1];
    const float* rk = (const float*)d_in[2];
    const float* bi = (const float*)d_in[3];
    const float* dw = (const float*)d_in[4];
    const float* db = (const float*)d_in[5];
    float* out = (float*)d_out;
    float* ws  = (float*)d_ws;

    const int Bt = in_sizes[0] / TF;  // 1048576
    prep_weights<<<1, BLOCK, 0, stream>>>(k, rk, bi, dw, db, ws);
    const int grid = (Bt + BLOCK - 1) / BLOCK;
    gru_main<<<grid, BLOCK, 0, stream>>>(x, ws, out, Bt);
}